// Round 1
// baseline (135.644 us; speedup 1.0000x reference)
//
#include <hip/hip_runtime.h>
#include <hip/hip_bf16.h>

typedef __attribute__((ext_vector_type(8))) short short8;   // 8 x bf16 (4 VGPRs)
typedef __attribute__((ext_vector_type(4))) float f32x4;
using bf16 = __hip_bfloat16;

// Problem sizes
// B=32, LQ=LKV=256, HID=1024, EMB=1024, K_fc=2048

__device__ __forceinline__ void glds16(const void* g, void* lds) {
  __builtin_amdgcn_global_load_lds(
      (const __attribute__((address_space(1))) void*)g,
      (__attribute__((address_space(3))) void*)lds, 16, 0, 0);
}

// ---------------- K1: row gather/convert to bf16 ----------------
// tasks 0..8191   : EA[task] = bf16(Wa[captions[task]])          (1024)
// tasks 8192..16383: X[t][0:1024] = bf16(H[t])                    (1024)
// tasks 16384..17407: FW[t] = bf16(fc_w[t])                       (2048)
__global__ __launch_bounds__(256) void k1_convert(
    const int* __restrict__ captions, const float* __restrict__ Wa,
    const float* __restrict__ H, const float* __restrict__ fcw,
    bf16* __restrict__ EA, bf16* __restrict__ X, bf16* __restrict__ FW) {
  int task = blockIdx.x;
  const float* src;
  bf16* dst;
  int n;
  if (task < 8192) {
    src = Wa + (size_t)captions[task] * 1024;
    dst = EA + (size_t)task * 1024;
    n = 1024;
  } else if (task < 16384) {
    int t = task - 8192;
    src = H + (size_t)t * 1024;
    dst = X + (size_t)t * 2048;
    n = 1024;
  } else {
    int t = task - 16384;
    src = fcw + (size_t)t * 2048;
    dst = FW + (size_t)t * 2048;
    n = 2048;
  }
  for (int c = threadIdx.x * 4; c < n; c += 1024) {
    float4 v = *(const float4*)(src + c);
    __hip_bfloat162 p0, p1;
    p0.x = __float2bfloat16(v.x); p0.y = __float2bfloat16(v.y);
    p1.x = __float2bfloat16(v.z); p1.y = __float2bfloat16(v.w);
    *(__hip_bfloat162*)(dst + c) = p0;
    *(__hip_bfloat162*)(dst + c + 2) = p1;
  }
}

// ---------------- K1b: gather + transpose Wc -> ECT[b][h][k] bf16 ----------------
__global__ __launch_bounds__(256) void k1b_gather_transpose(
    const int* __restrict__ targets, const float* __restrict__ Wc,
    bf16* __restrict__ ECT) {
  __shared__ float T[64][67];  // pad 67: 2-way (free) bank aliasing on reads
  int bid = blockIdx.x;
  int b = bid >> 6;
  int kt = (bid >> 4) & 3;
  int ht = bid & 15;
  int tid = threadIdx.x;
#pragma unroll
  for (int p = 0; p < 4; ++p) {
    int k = p * 16 + (tid >> 4);
    int idx = targets[b * 256 + kt * 64 + k];
    const float* s = Wc + (size_t)idx * 1024 + ht * 64 + (tid & 15) * 4;
    float4 v = *(const float4*)s;
    int c = (tid & 15) * 4;
    T[k][c] = v.x; T[k][c + 1] = v.y; T[k][c + 2] = v.z; T[k][c + 3] = v.w;
  }
  __syncthreads();
#pragma unroll
  for (int p = 0; p < 8; ++p) {
    int h = p * 8 + (tid >> 5);
    int k = (tid & 31) * 2;
    __hip_bfloat162 o;
    o.x = __float2bfloat16(T[k][h]);
    o.y = __float2bfloat16(T[k + 1][h]);
    *(__hip_bfloat162*)(ECT + ((size_t)b * 1024 + ht * 64 + h) * 256 + kt * 64 + k) = o;
  }
}

// ---------------- K2: u = H @ EA^T, fused masked-exp softmax -> P bf16 ----------------
// BM=64, BN=256 (full KV row in-block), BK=64, 4 waves, wave = 16 rows x 256 cols
__global__ __launch_bounds__(256) void k2_scores_softmax(
    const bf16* __restrict__ X, const bf16* __restrict__ EA,
    const float* __restrict__ mask, bf16* __restrict__ P) {
  __shared__ __align__(16) bf16 As[64 * 64];
  __shared__ __align__(16) bf16 Bs[256 * 64];
  int b = blockIdx.x >> 2;
  int mb = blockIdx.x & 3;
  int tid = threadIdx.x;
  int w = tid >> 6, l = tid & 63;
  f32x4 acc[16];
  f32x4 zero = {0.f, 0.f, 0.f, 0.f};
#pragma unroll
  for (int n = 0; n < 16; ++n) acc[n] = zero;

  const bf16* Ag = X + ((size_t)b * 256 + mb * 64) * 2048;  // H bf16, row stride 2048
  const bf16* Bg = EA + (size_t)b * 256 * 1024;             // row stride 1024

  for (int kt = 0; kt < 16; ++kt) {
#pragma unroll
    for (int i = 0; i < 2; ++i) {  // A tile: 64 rows x 64 k (8 KB)
      int c = i * 256 + tid;
      int row = c >> 3, slot = c & 7;
      int ss = slot ^ (row & 7);
      glds16(Ag + (size_t)row * 2048 + kt * 64 + ss * 8,
             As + (size_t)(i * 256 + w * 64) * 8);
    }
#pragma unroll
    for (int i = 0; i < 8; ++i) {  // B tile: 256 rows x 64 k (32 KB)
      int c = i * 256 + tid;
      int row = c >> 3, slot = c & 7;
      int ss = slot ^ (row & 7);
      glds16(Bg + (size_t)row * 1024 + kt * 64 + ss * 8,
             Bs + (size_t)(i * 256 + w * 64) * 8);
    }
    __syncthreads();
#pragma unroll
    for (int kk = 0; kk < 2; ++kk) {
      int arow = w * 16 + (l & 15);
      int aslot = kk * 4 + (l >> 4);
      short8 af = *(const short8*)(As + arow * 64 + ((aslot ^ (arow & 7)) * 8));
#pragma unroll
      for (int n = 0; n < 16; ++n) {
        int brow = n * 16 + (l & 15);
        int bslot = kk * 4 + (l >> 4);
        short8 bfr = *(const short8*)(Bs + brow * 64 + ((bslot ^ (brow & 7)) * 8));
        acc[n] = __builtin_amdgcn_mfma_f32_16x16x32_bf16(af, bfr, acc[n], 0, 0, 0);
      }
    }
    __syncthreads();
  }
  // Softmax epilogue. Lane holds rows q0..q0+3 (via reg i), cols (l&15)+16n.
  int q0 = mb * 64 + w * 16 + ((l >> 4) << 2);
  const float* mrow = mask + ((size_t)b * 256 + q0) * 256;
  float s[4] = {0.f, 0.f, 0.f, 0.f};
#pragma unroll
  for (int n = 0; n < 16; ++n) {
    int col = (l & 15) + 16 * n;
#pragma unroll
    for (int i = 0; i < 4; ++i) {
      float mv = mrow[i * 256 + col];
      mv = fminf(fmaxf(mv, 0.f), 1.f);
      float ev = expf(acc[n][i]) * mv;
      acc[n][i] = ev;
      s[i] += ev;
    }
  }
#pragma unroll
  for (int m = 1; m < 16; m <<= 1) {
#pragma unroll
    for (int i = 0; i < 4; ++i) s[i] += __shfl_xor(s[i], m, 64);
  }
  bf16* Prow = P + ((size_t)b * 256 + q0) * 256;
#pragma unroll
  for (int i = 0; i < 4; ++i) {
    float inv = 1.f / (s[i] + 1e-10f);
#pragma unroll
    for (int n = 0; n < 16; ++n) {
      int col = (l & 15) + 16 * n;
      Prow[i * 256 + col] = __float2bfloat16(acc[n][i] * inv);
    }
  }
}

// ---------------- K3: o = P @ EC  (B operand = ECT, k-contiguous), write X[:,1024:] ----------------
// M=256,N=1024,K=256 per batch; BM=BN=128, BK=64, 4 waves 2x2, wave = 64x64
__global__ __launch_bounds__(256) void k3_pv(
    const bf16* __restrict__ P, const bf16* __restrict__ ECT,
    bf16* __restrict__ X) {
  __shared__ __align__(16) bf16 As[128 * 64];
  __shared__ __align__(16) bf16 Bs[128 * 64];
  int bid = blockIdx.x;
  int b = bid >> 4;
  int mb = (bid >> 3) & 1;
  int nb = bid & 7;
  int tid = threadIdx.x, w = tid >> 6, l = tid & 63;
  int wr = w >> 1, wc = w & 1;
  f32x4 acc[4][4];
  f32x4 zero = {0.f, 0.f, 0.f, 0.f};
#pragma unroll
  for (int m = 0; m < 4; ++m)
#pragma unroll
    for (int n = 0; n < 4; ++n) acc[m][n] = zero;
  const bf16* Ag = P + (size_t)b * 256 * 256 + mb * 128 * 256;
  const bf16* Bg = ECT + (size_t)b * 1024 * 256 + nb * 128 * 256;
  for (int kt = 0; kt < 4; ++kt) {
#pragma unroll
    for (int i = 0; i < 4; ++i) {
      int c = i * 256 + tid;
      int row = c >> 3, slot = c & 7, ss = slot ^ (row & 7);
      glds16(Ag + (size_t)row * 256 + kt * 64 + ss * 8,
             As + (size_t)(i * 256 + w * 64) * 8);
    }
#pragma unroll
    for (int i = 0; i < 4; ++i) {
      int c = i * 256 + tid;
      int row = c >> 3, slot = c & 7, ss = slot ^ (row & 7);
      glds16(Bg + (size_t)row * 256 + kt * 64 + ss * 8,
             Bs + (size_t)(i * 256 + w * 64) * 8);
    }
    __syncthreads();
#pragma unroll
    for (int kk = 0; kk < 2; ++kk) {
      short8 a[4], bb[4];
#pragma unroll
      for (int m = 0; m < 4; ++m) {
        int row = wr * 64 + m * 16 + (l & 15);
        int slot = kk * 4 + (l >> 4);
        a[m] = *(const short8*)(As + row * 64 + ((slot ^ (row & 7)) * 8));
      }
#pragma unroll
      for (int n = 0; n < 4; ++n) {
        int row = wc * 64 + n * 16 + (l & 15);
        int slot = kk * 4 + (l >> 4);
        bb[n] = *(const short8*)(Bs + row * 64 + ((slot ^ (row & 7)) * 8));
      }
#pragma unroll
      for (int m = 0; m < 4; ++m)
#pragma unroll
        for (int n = 0; n < 4; ++n)
          acc[m][n] = __builtin_amdgcn_mfma_f32_16x16x32_bf16(a[m], bb[n], acc[m][n], 0, 0, 0);
    }
    __syncthreads();
  }
#pragma unroll
  for (int m = 0; m < 4; ++m) {
    int rbase = b * 256 + mb * 128 + wr * 64 + m * 16 + ((l >> 4) << 2);
#pragma unroll
    for (int n = 0; n < 4; ++n) {
      int col = 1024 + nb * 128 + wc * 64 + n * 16 + (l & 15);
#pragma unroll
      for (int i = 0; i < 4; ++i)
        X[(size_t)(rbase + i) * 2048 + col] = __float2bfloat16(acc[m][n][i]);
    }
  }
}

// ---------------- K4: out = X @ FW^T + fc_b + 1e-10 (f32) ----------------
// M=8192, N=1024, K=2048; BM=BN=128, BK=64
__global__ __launch_bounds__(256) void k4_fc(
    const bf16* __restrict__ X, const bf16* __restrict__ FW,
    const float* __restrict__ fcb, float* __restrict__ out) {
  __shared__ __align__(16) bf16 As[128 * 64];
  __shared__ __align__(16) bf16 Bs[128 * 64];
  int bid = blockIdx.x;
  int mb = bid >> 3;
  int nb = bid & 7;
  int tid = threadIdx.x, w = tid >> 6, l = tid & 63;
  int wr = w >> 1, wc = w & 1;
  f32x4 acc[4][4];
  f32x4 zero = {0.f, 0.f, 0.f, 0.f};
#pragma unroll
  for (int m = 0; m < 4; ++m)
#pragma unroll
    for (int n = 0; n < 4; ++n) acc[m][n] = zero;
  const bf16* Ag = X + (size_t)mb * 128 * 2048;
  const bf16* Bg = FW + (size_t)nb * 128 * 2048;
  for (int kt = 0; kt < 32; ++kt) {
#pragma unroll
    for (int i = 0; i < 4; ++i) {
      int c = i * 256 + tid;
      int row = c >> 3, slot = c & 7, ss = slot ^ (row & 7);
      glds16(Ag + (size_t)row * 2048 + kt * 64 + ss * 8,
             As + (size_t)(i * 256 + w * 64) * 8);
    }
#pragma unroll
    for (int i = 0; i < 4; ++i) {
      int c = i * 256 + tid;
      int row = c >> 3, slot = c & 7, ss = slot ^ (row & 7);
      glds16(Bg + (size_t)row * 2048 + kt * 64 + ss * 8,
             Bs + (size_t)(i * 256 + w * 64) * 8);
    }
    __syncthreads();
#pragma unroll
    for (int kk = 0; kk < 2; ++kk) {
      short8 a[4], bb[4];
#pragma unroll
      for (int m = 0; m < 4; ++m) {
        int row = wr * 64 + m * 16 + (l & 15);
        int slot = kk * 4 + (l >> 4);
        a[m] = *(const short8*)(As + row * 64 + ((slot ^ (row & 7)) * 8));
      }
#pragma unroll
      for (int n = 0; n < 4; ++n) {
        int row = wc * 64 + n * 16 + (l & 15);
        int slot = kk * 4 + (l >> 4);
        bb[n] = *(const short8*)(Bs + row * 64 + ((slot ^ (row & 7)) * 8));
      }
#pragma unroll
      for (int m = 0; m < 4; ++m)
#pragma unroll
        for (int n = 0; n < 4; ++n)
          acc[m][n] = __builtin_amdgcn_mfma_f32_16x16x32_bf16(a[m], bb[n], acc[m][n], 0, 0, 0);
    }
    __syncthreads();
  }
  float bias[4];
#pragma unroll
  for (int n = 0; n < 4; ++n)
    bias[n] = fcb[nb * 128 + wc * 64 + n * 16 + (l & 15)];
#pragma unroll
  for (int m = 0; m < 4; ++m) {
    int rbase = mb * 128 + wr * 64 + m * 16 + ((l >> 4) << 2);
#pragma unroll
    for (int n = 0; n < 4; ++n) {
      int col = nb * 128 + wc * 64 + n * 16 + (l & 15);
#pragma unroll
      for (int i = 0; i < 4; ++i)
        out[(size_t)(rbase + i) * 1024 + col] = acc[m][n][i] + bias[n] + 1e-10f;
    }
  }
}

// ---------------- K5: in-place row L2 normalize ----------------
__global__ __launch_bounds__(256) void k5_norm(float* __restrict__ y) {
  __shared__ float red[4];
  int row = blockIdx.x;
  float* p = y + (size_t)row * 1024;
  int tid = threadIdx.x;
  float4 v = *(const float4*)(p + tid * 4);
  float ss = v.x * v.x + v.y * v.y + v.z * v.z + v.w * v.w;
#pragma unroll
  for (int m = 1; m < 64; m <<= 1) ss += __shfl_xor(ss, m, 64);
  if ((tid & 63) == 0) red[tid >> 6] = ss;
  __syncthreads();
  float tot = red[0] + red[1] + red[2] + red[3];
  float inv = 1.f / (sqrtf(tot) + 1e-8f);
  float4 o;
  o.x = v.x * inv; o.y = v.y * inv; o.z = v.z * inv; o.w = v.w * inv;
  *(float4*)(p + tid * 4) = o;
}

extern "C" void kernel_launch(void* const* d_in, const int* in_sizes, int n_in,
                              void* d_out, int out_size, void* d_ws, size_t ws_size,
                              hipStream_t stream) {
  const int* captions = (const int*)d_in[0];
  const float* H = (const float*)d_in[1];
  const int* targets = (const int*)d_in[2];
  const float* mask = (const float*)d_in[3];
  const float* Wa = (const float*)d_in[4];
  const float* Wc = (const float*)d_in[5];
  const float* fcw = (const float*)d_in[6];
  const float* fcb = (const float*)d_in[7];
  float* out = (float*)d_out;

  char* ws = (char*)d_ws;
  bf16* EA = (bf16*)(ws);                        // 16 MB [32][256][1024]
  bf16* ECT = (bf16*)(ws + (16u << 20));         // 16 MB [32][1024][256]
  bf16* P = (bf16*)(ws + (32u << 20));           //  4 MB [32][256][256]
  bf16* X = (bf16*)(ws + (36u << 20));           // 32 MB [8192][2048]
  bf16* FW = (bf16*)(ws + (68u << 20));          //  4 MB [1024][2048]

  k1_convert<<<17408, 256, 0, stream>>>(captions, Wa, H, fcw, EA, X, FW);
  k1b_gather_transpose<<<2048, 256, 0, stream>>>(targets, Wc, ECT);
  k2_scores_softmax<<<128, 256, 0, stream>>>(X, EA, mask, P);
  k3_pv<<<512, 256, 0, stream>>>(P, ECT, X);
  k4_fc<<<512, 256, 0, stream>>>(X, FW, fcb, out);
  k5_norm<<<8192, 256, 0, stream>>>(out);
}

// Round 4
// 128.128 us; speedup vs baseline: 1.0587x; 1.0587x over previous
//
#include <hip/hip_runtime.h>
#include <hip/hip_bf16.h>

typedef __attribute__((ext_vector_type(8))) short short8;   // 8 x bf16 (4 VGPRs)
typedef __attribute__((ext_vector_type(4))) float f32x4;
using bf16 = __hip_bfloat16;

// Problem sizes: B=32, LQ=LKV=256, HID=1024, EMB=1024, K_fc=2048

__device__ __forceinline__ void glds16(const void* g, void* lds) {
  __builtin_amdgcn_global_load_lds(
      (const __attribute__((address_space(1))) void*)g,
      (__attribute__((address_space(3))) void*)lds, 16, 0, 0);
}

// ---------------- K1: row gather/convert to bf16 ----------------
__global__ __launch_bounds__(256) void k1_convert(
    const int* __restrict__ captions, const float* __restrict__ Wa,
    const float* __restrict__ H, const float* __restrict__ fcw,
    bf16* __restrict__ EA, bf16* __restrict__ X, bf16* __restrict__ FW) {
  int task = blockIdx.x;
  const float* src;
  bf16* dst;
  int n;
  if (task < 8192) {
    src = Wa + (size_t)captions[task] * 1024;
    dst = EA + (size_t)task * 1024;
    n = 1024;
  } else if (task < 16384) {
    int t = task - 8192;
    src = H + (size_t)t * 1024;
    dst = X + (size_t)t * 2048;
    n = 1024;
  } else {
    int t = task - 16384;
    src = fcw + (size_t)t * 2048;
    dst = FW + (size_t)t * 2048;
    n = 2048;
  }
  for (int c = threadIdx.x * 4; c < n; c += 1024) {
    float4 v = *(const float4*)(src + c);
    __hip_bfloat162 p0, p1;
    p0.x = __float2bfloat16(v.x); p0.y = __float2bfloat16(v.y);
    p1.x = __float2bfloat16(v.z); p1.y = __float2bfloat16(v.w);
    *(__hip_bfloat162*)(dst + c) = p0;
    *(__hip_bfloat162*)(dst + c + 2) = p1;
  }
}

// ---------------- K1b: gather + transpose Wc -> ECT[b][h][k] bf16 ----------------
__global__ __launch_bounds__(256) void k1b_gather_transpose(
    const int* __restrict__ targets, const float* __restrict__ Wc,
    bf16* __restrict__ ECT) {
  __shared__ float T[64][67];
  int bid = blockIdx.x;
  int b = bid >> 6;
  int kt = (bid >> 4) & 3;
  int ht = bid & 15;
  int tid = threadIdx.x;
#pragma unroll
  for (int p = 0; p < 4; ++p) {
    int k = p * 16 + (tid >> 4);
    int idx = targets[b * 256 + kt * 64 + k];
    const float* s = Wc + (size_t)idx * 1024 + ht * 64 + (tid & 15) * 4;
    float4 v = *(const float4*)s;
    int c = (tid & 15) * 4;
    T[k][c] = v.x; T[k][c + 1] = v.y; T[k][c + 2] = v.z; T[k][c + 3] = v.w;
  }
  __syncthreads();
#pragma unroll
  for (int p = 0; p < 8; ++p) {
    int h = p * 8 + (tid >> 5);
    int k = (tid & 31) * 2;
    __hip_bfloat162 o;
    o.x = __float2bfloat16(T[k][h]);
    o.y = __float2bfloat16(T[k + 1][h]);
    *(__hip_bfloat162*)(ECT + ((size_t)b * 1024 + ht * 64 + h) * 256 + kt * 64 + k) = o;
  }
}

// ---------------- K2: u = H @ EA^T, fused masked-exp softmax -> P bf16 ----------------
__global__ __launch_bounds__(256) void k2_scores_softmax(
    const bf16* __restrict__ X, const bf16* __restrict__ EA,
    const float* __restrict__ mask, bf16* __restrict__ P) {
  __shared__ __align__(16) bf16 As[64 * 64];
  __shared__ __align__(16) bf16 Bs[256 * 64];
  int b = blockIdx.x >> 2;
  int mb = blockIdx.x & 3;
  int tid = threadIdx.x;
  int w = tid >> 6, l = tid & 63;
  f32x4 acc[16];
  f32x4 zero = {0.f, 0.f, 0.f, 0.f};
#pragma unroll
  for (int n = 0; n < 16; ++n) acc[n] = zero;

  const bf16* Ag = X + ((size_t)b * 256 + mb * 64) * 2048;
  const bf16* Bg = EA + (size_t)b * 256 * 1024;

  for (int kt = 0; kt < 16; ++kt) {
#pragma unroll
    for (int i = 0; i < 2; ++i) {
      int c = i * 256 + tid;
      int row = c >> 3, slot = c & 7;
      int ss = slot ^ (row & 7);
      glds16(Ag + (size_t)row * 2048 + kt * 64 + ss * 8,
             As + (size_t)(i * 256 + w * 64) * 8);
    }
#pragma unroll
    for (int i = 0; i < 8; ++i) {
      int c = i * 256 + tid;
      int row = c >> 3, slot = c & 7;
      int ss = slot ^ (row & 7);
      glds16(Bg + (size_t)row * 1024 + kt * 64 + ss * 8,
             Bs + (size_t)(i * 256 + w * 64) * 8);
    }
    __syncthreads();
#pragma unroll
    for (int kk = 0; kk < 2; ++kk) {
      int arow = w * 16 + (l & 15);
      int aslot = kk * 4 + (l >> 4);
      short8 af = *(const short8*)(As + arow * 64 + ((aslot ^ (arow & 7)) * 8));
#pragma unroll
      for (int n = 0; n < 16; ++n) {
        int brow = n * 16 + (l & 15);
        int bslot = kk * 4 + (l >> 4);
        short8 bfr = *(const short8*)(Bs + brow * 64 + ((bslot ^ (brow & 7)) * 8));
        acc[n] = __builtin_amdgcn_mfma_f32_16x16x32_bf16(af, bfr, acc[n], 0, 0, 0);
      }
    }
    __syncthreads();
  }
  int q0 = mb * 64 + w * 16 + ((l >> 4) << 2);
  const float* mrow = mask + ((size_t)b * 256 + q0) * 256;
  float s[4] = {0.f, 0.f, 0.f, 0.f};
#pragma unroll
  for (int n = 0; n < 16; ++n) {
    int col = (l & 15) + 16 * n;
#pragma unroll
    for (int i = 0; i < 4; ++i) {
      float mv = mrow[i * 256 + col];
      mv = fminf(fmaxf(mv, 0.f), 1.f);
      float ev = expf(acc[n][i]) * mv;
      acc[n][i] = ev;
      s[i] += ev;
    }
  }
#pragma unroll
  for (int m = 1; m < 16; m <<= 1) {
#pragma unroll
    for (int i = 0; i < 4; ++i) s[i] += __shfl_xor(s[i], m, 64);
  }
  bf16* Prow = P + ((size_t)b * 256 + q0) * 256;
#pragma unroll
  for (int i = 0; i < 4; ++i) {
    float inv = 1.f / (s[i] + 1e-10f);
#pragma unroll
    for (int n = 0; n < 16; ++n) {
      int col = (l & 15) + 16 * n;
      Prow[i * 256 + col] = __float2bfloat16(acc[n][i] * inv);
    }
  }
}

// ---------------- K3: o = P @ EC  -> X[:,1024:] ----------------
__global__ __launch_bounds__(256) void k3_pv(
    const bf16* __restrict__ P, const bf16* __restrict__ ECT,
    bf16* __restrict__ X) {
  __shared__ __align__(16) bf16 As[128 * 64];
  __shared__ __align__(16) bf16 Bs[128 * 64];
  int bid = blockIdx.x;
  int b = bid >> 4;
  int mb = (bid >> 3) & 1;
  int nb = bid & 7;
  int tid = threadIdx.x, w = tid >> 6, l = tid & 63;
  int wr = w >> 1, wc = w & 1;
  f32x4 acc[4][4];
  f32x4 zero = {0.f, 0.f, 0.f, 0.f};
#pragma unroll
  for (int m = 0; m < 4; ++m)
#pragma unroll
    for (int n = 0; n < 4; ++n) acc[m][n] = zero;
  const bf16* Ag = P + (size_t)b * 256 * 256 + mb * 128 * 256;
  const bf16* Bg = ECT + (size_t)b * 1024 * 256 + nb * 128 * 256;
  for (int kt = 0; kt < 4; ++kt) {
#pragma unroll
    for (int i = 0; i < 4; ++i) {
      int c = i * 256 + tid;
      int row = c >> 3, slot = c & 7, ss = slot ^ (row & 7);
      glds16(Ag + (size_t)row * 256 + kt * 64 + ss * 8,
             As + (size_t)(i * 256 + w * 64) * 8);
    }
#pragma unroll
    for (int i = 0; i < 4; ++i) {
      int c = i * 256 + tid;
      int row = c >> 3, slot = c & 7, ss = slot ^ (row & 7);
      glds16(Bg + (size_t)row * 256 + kt * 64 + ss * 8,
             Bs + (size_t)(i * 256 + w * 64) * 8);
    }
    __syncthreads();
#pragma unroll
    for (int kk = 0; kk < 2; ++kk) {
      short8 a[4], bb[4];
#pragma unroll
      for (int m = 0; m < 4; ++m) {
        int row = wr * 64 + m * 16 + (l & 15);
        int slot = kk * 4 + (l >> 4);
        a[m] = *(const short8*)(As + row * 64 + ((slot ^ (row & 7)) * 8));
      }
#pragma unroll
      for (int n = 0; n < 4; ++n) {
        int row = wc * 64 + n * 16 + (l & 15);
        int slot = kk * 4 + (l >> 4);
        bb[n] = *(const short8*)(Bs + row * 64 + ((slot ^ (row & 7)) * 8));
      }
#pragma unroll
      for (int m = 0; m < 4; ++m)
#pragma unroll
        for (int n = 0; n < 4; ++n)
          acc[m][n] = __builtin_amdgcn_mfma_f32_16x16x32_bf16(a[m], bb[n], acc[m][n], 0, 0, 0);
    }
    __syncthreads();
  }
#pragma unroll
  for (int m = 0; m < 4; ++m) {
    int rbase = b * 256 + mb * 128 + wr * 64 + m * 16 + ((l >> 4) << 2);
#pragma unroll
    for (int n = 0; n < 4; ++n) {
      int col = 1024 + nb * 128 + wc * 64 + n * 16 + (l & 15);
#pragma unroll
      for (int i = 0; i < 4; ++i)
        X[(size_t)(rbase + i) * 2048 + col] = __float2bfloat16(acc[m][n][i]);
    }
  }
}

// ---------------- K4: out = X @ FW^T + fc_b + 1e-10 (f32) ----------------
// M=8192, N=1024, K=2048; BM=BN=128, BK=64; 256 thr (4 waves 2x2), wave 64x64.
// 2-phase double-buffer (T3 minimum recipe): STAGE(t+1)->alt; compute cur;
// __syncthreads() (implicit vmcnt(0)+lgkmcnt(0) = compiler-proof acquire AND
// release — no counted vmcnt anywhere). 64KB LDS -> 2 blocks/CU; grid 512 = 2/CU.
// Chunked XCD swizzle: all 8 A-panel-sharing blocks land on one XCD's L2.
#define K4T (128 * 64)

__device__ __forceinline__ void k4_stage(const bf16* __restrict__ Ag,
                                         const bf16* __restrict__ Bg, int kt,
                                         bf16* As, bf16* Bs, int tid, int w) {
#pragma unroll
  for (int i = 0; i < 4; ++i) {
    int c = i * 256 + tid;
    int row = c >> 3, ss = (c & 7) ^ (row & 7);
    glds16(Ag + (size_t)row * 2048 + kt * 64 + ss * 8,
           As + (size_t)(i * 256 + w * 64) * 8);
  }
#pragma unroll
  for (int i = 0; i < 4; ++i) {
    int c = i * 256 + tid;
    int row = c >> 3, ss = (c & 7) ^ (row & 7);
    glds16(Bg + (size_t)row * 2048 + kt * 64 + ss * 8,
           Bs + (size_t)(i * 256 + w * 64) * 8);
  }
}

__device__ __forceinline__ void k4_tile(const bf16* As, const bf16* Bs,
                                        int wr, int wc, int l,
                                        f32x4 (&acc)[4][4]) {
  short8 a[2][4], b[2][4];
#pragma unroll
  for (int kk = 0; kk < 2; ++kk)
#pragma unroll
    for (int n = 0; n < 4; ++n) {
      int row = wc * 64 + n * 16 + (l & 15);
      int slot = kk * 4 + (l >> 4);
      b[kk][n] = *(const short8*)(Bs + row * 64 + ((slot ^ (row & 7)) * 8));
    }
#pragma unroll
  for (int kk = 0; kk < 2; ++kk)
#pragma unroll
    for (int m = 0; m < 4; ++m) {
      int row = wr * 64 + m * 16 + (l & 15);
      int slot = kk * 4 + (l >> 4);
      a[kk][m] = *(const short8*)(As + row * 64 + ((slot ^ (row & 7)) * 8));
    }
  __builtin_amdgcn_s_setprio(1);
#pragma unroll
  for (int kk = 0; kk < 2; ++kk)
#pragma unroll
    for (int m = 0; m < 4; ++m)
#pragma unroll
      for (int n = 0; n < 4; ++n)
        acc[m][n] = __builtin_amdgcn_mfma_f32_16x16x32_bf16(
            a[kk][m], b[kk][n], acc[m][n], 0, 0, 0);
  __builtin_amdgcn_s_setprio(0);
}

__global__ __launch_bounds__(256, 2) void k4_fc(
    const bf16* __restrict__ X, const bf16* __restrict__ FW,
    const float* __restrict__ fcb, float* __restrict__ out) {
  __shared__ __align__(16) bf16 As[2][K4T];   // 32 KB
  __shared__ __align__(16) bf16 Bs[2][K4T];   // 32 KB
  int p = blockIdx.x;
  int wg = (p & 7) * 64 + (p >> 3);   // chunked XCD swizzle (512 % 8 == 0)
  int mb = wg >> 3;   // 0..63
  int nb = wg & 7;    // 0..7
  int tid = threadIdx.x, w = tid >> 6, l = tid & 63;
  int wr = w >> 1, wc = w & 1;
  f32x4 acc[4][4];
  f32x4 zero = {0.f, 0.f, 0.f, 0.f};
#pragma unroll
  for (int m = 0; m < 4; ++m)
#pragma unroll
    for (int n = 0; n < 4; ++n) acc[m][n] = zero;

  const bf16* Ag = X + (size_t)mb * 128 * 2048;
  const bf16* Bg = FW + (size_t)nb * 128 * 2048;

  k4_stage(Ag, Bg, 0, As[0], Bs[0], tid, w);
  __syncthreads();
  for (int t = 0; t < 32; ++t) {
    int cur = t & 1;
    if (t < 31)
      k4_stage(Ag, Bg, t + 1, As[cur ^ 1], Bs[cur ^ 1], tid, w);
    k4_tile(As[cur], Bs[cur], wr, wc, l, acc);
    __syncthreads();   // drains vmcnt(0)+lgkmcnt(0): acquire t+1, release cur
  }

  float bias[4];
#pragma unroll
  for (int n = 0; n < 4; ++n)
    bias[n] = fcb[nb * 128 + wc * 64 + n * 16 + (l & 15)];
#pragma unroll
  for (int m = 0; m < 4; ++m) {
    int rbase = mb * 128 + wr * 64 + m * 16 + ((l >> 4) << 2);
#pragma unroll
    for (int n = 0; n < 4; ++n) {
      int col = nb * 128 + wc * 64 + n * 16 + (l & 15);
#pragma unroll
      for (int i = 0; i < 4; ++i)
        out[(size_t)(rbase + i) * 1024 + col] = acc[m][n][i] + bias[n] + 1e-10f;
    }
  }
}

// ---------------- K5: in-place row L2 normalize ----------------
__global__ __launch_bounds__(256) void k5_norm(float* __restrict__ y) {
  __shared__ float red[4];
  int row = blockIdx.x;
  float* p = y + (size_t)row * 1024;
  int tid = threadIdx.x;
  float4 v = *(const float4*)(p + tid * 4);
  float ss = v.x * v.x + v.y * v.y + v.z * v.z + v.w * v.w;
#pragma unroll
  for (int m = 1; m < 64; m <<= 1) ss += __shfl_xor(ss, m, 64);
  if ((tid & 63) == 0) red[tid >> 6] = ss;
  __syncthreads();
  float tot = red[0] + red[1] + red[2] + red[3];
  float inv = 1.f / (sqrtf(tot) + 1e-8f);
  float4 o;
  o.x = v.x * inv; o.y = v.y * inv; o.z = v.z * inv; o.w = v.w * inv;
  *(float4*)(p + tid * 4) = o;
}

extern "C" void kernel_launch(void* const* d_in, const int* in_sizes, int n_in,
                              void* d_out, int out_size, void* d_ws, size_t ws_size,
                              hipStream_t stream) {
  const int* captions = (const int*)d_in[0];
  const float* H = (const float*)d_in[1];
  const int* targets = (const int*)d_in[2];
  const float* mask = (const float*)d_in[3];
  const float* Wa = (const float*)d_in[4];
  const float* Wc = (const float*)d_in[5];
  const float* fcw = (const float*)d_in[6];
  const float* fcb = (const float*)d_in[7];
  float* out = (float*)d_out;

  char* ws = (char*)d_ws;
  bf16* EA = (bf16*)(ws);                        // 16 MB [32][256][1024]
  bf16* ECT = (bf16*)(ws + (16u << 20));         // 16 MB [32][1024][256]
  bf16* P = (bf16*)(ws + (32u << 20));           //  4 MB [32][256][256]
  bf16* X = (bf16*)(ws + (36u << 20));           // 32 MB [8192][2048]
  bf16* FW = (bf16*)(ws + (68u << 20));          //  4 MB [1024][2048]

  k1_convert<<<17408, 256, 0, stream>>>(captions, Wa, H, fcw, EA, X, FW);
  k1b_gather_transpose<<<2048, 256, 0, stream>>>(targets, Wc, ECT);
  k2_scores_softmax<<<128, 256, 0, stream>>>(X, EA, mask, P);
  k3_pv<<<512, 256, 0, stream>>>(P, ECT, X);
  k4_fc<<<512, 256, 0, stream>>>(X, FW, fcb, out);
  k5_norm<<<8192, 256, 0, stream>>>(out);
}